// Round 9
// baseline (482.073 us; speedup 1.0000x reference)
//
#include <hip/hip_runtime.h>
#include <math.h>

// B=32, C=3, H=W=512, window 11, sigma 1.5, VALID conv -> 502x502
#define H 512
#define W 512
#define OUT_H 502
#define OUT_W 502
#define C1c 1.0e-4f   // (0.01*1)^2
#define C2c 9.0e-4f   // (0.03*1)^2

#define TH 144            // output rows per block
#define NR 154            // TH+10 input rows = 7*22 (pair- and phase-aligned)
#define HALO 10
#define SPAN 64           // output cols per WAVE (wave-private strip)
#define SLOTQ 80          // float4 entries per row-slot per wave (74 used)

// Row-streaming SSIM, wave-private staging, barrier-free, PAIR-ROW pipeline.
// (R9 = R8 resubmitted: R8's bench died on container infra, no kernel verdict;
//  audit of phase algebra / coverage / bounds found no defect.)
//   Rationale: occupancy is pinned at ~2.6 waves/SIMD in EVERY config tried
//   (grid 960-3456, blocks 128-512, LDS 1.5-5KB) -> TLP is capped; and
//   VALUBusy*dur ~= 110-119us in every round -> VALU-issue-bound at 73-85%
//   efficiency. Pairing gives the scheduler two independent h-pass chains
//   per wave (row r+1's ds_reads issue under row r's FMAs) and halves
//   per-row loop/branch/address/halo-mask overhead.
//   float4 staging kept (R5->R6 A/B: trading 1 LDS op for 22 VALU lost 9us).
//  - wave-private strips: DS ops in-order within a wave -> no s_barrier, no
//    per-row vmcnt/lgkmcnt drain; wave_barrier only pins compiler order.
//  - two row-slots (A,B); pair i+1's writes follow pair i's reads in program
//    order -> in-order DS pipe makes the single-buffer reuse safe.
//  - 55 phase accumulators, first-write-mul; weights in SGPR.
//  - retile NR=154/TH=144: 4 row-tiles, staged rows 616/col-tile (R5: 605).
__global__ __launch_bounds__(256, 4)
void ssim_kernel(const float* __restrict__ img1,
                 const float* __restrict__ img2,
                 float* __restrict__ out) {
    __shared__ float4 stg[4][2][SLOTQ];   // [wave][rowslot][col], 10240 B
    __shared__ float wsum[4];

    const int tid  = threadIdx.x;
    const int wid  = tid >> 6;
    const int lane = tid & 63;

    // Gaussian weights (runtime expf to match reference), pinned to SGPR
    float g[11];
    {
        float s = 0.f;
#pragma unroll
        for (int i = 0; i < 11; ++i) {
            float d = (float)(i - 5);
            g[i] = expf(-d * d * (1.0f / 4.5f));
            s += g[i];
        }
        float inv = 1.0f / s;
#pragma unroll
        for (int i = 0; i < 11; ++i) {
            g[i] *= inv;
            g[i] = __uint_as_float(__builtin_amdgcn_readfirstlane(__float_as_uint(g[i])));
        }
    }

    const int base = blockIdx.x * 256 + wid * SPAN;  // strip origin
    const int oyb  = blockIdx.y * TH;                // output rows owned
    const int Y0   = min(oyb, H - NR);               // shift last tile up
    const int plane = blockIdx.z;                    // b*3 + c
    const size_t pbase = (size_t)plane * (H * W);
    const float* __restrict__ p1 = img1 + pbase;
    const float* __restrict__ p2 = img2 + pbase;

    const int gx = base + lane;                      // main column (<512)
    const int hx = min(base + SPAN + lane, W - 1);   // halo column (lanes<10)
    const float cmask = (gx < OUT_W) ? 1.0f : 0.0f;  // discard cols 502..511
    const bool hl = (lane < HALO);

    // per-lane column bases; row offset ro stays wave-uniform (SALU)
    const float* __restrict__ q1  = p1 + gx;
    const float* __restrict__ q2  = p2 + gx;
    const float* __restrict__ qh1 = p1 + hx;
    const float* __restrict__ qh2 = p2 + hx;

    float4* const stA = stg[wid][0];
    float4* const stB = stg[wid][1];

    // 11 phase slots of vertical partial sums, 5 quantities
    float a0[11], a1q[11], a2q[11], a3q[11], a4q[11];
#pragma unroll
    for (int i = 0; i < 11; ++i) { a0[i]=0.f; a1q[i]=0.f; a2q[i]=0.f; a3q[i]=0.f; a4q[i]=0.f; }

    float lsum = 0.f;

    int ro = Y0 * W;
    const int rocap = (H - 2) * W;   // ro+W stays in-bounds after clamp

    // prime prefetch (rows Y0, Y0+1)
    float a1 = q1[ro],     a2 = q2[ro];
    float b1 = q1[ro + W], b2 = q2[ro + W];
    float ha1 = 0.f, ha2 = 0.f, hb1 = 0.f, hb2 = 0.f;
    if (hl) { ha1 = qh1[ro]; ha2 = qh2[ro]; hb1 = qh1[ro + W]; hb2 = qh2[ro + W]; }

#pragma unroll 1
    for (int rb = 0; rb < NR; rb += 22) {
#pragma unroll
        for (int i = 0; i < 11; ++i) {
            const int p  = (2 * i) % 11;        // phase of row r (compile-time)
            const int pp = (p + 1) % 11;        // phase of row r+1
            const int r  = rb + 2 * i;

            // stage the pair: float4(x1, x2, x1*x2, x1^2); x2^2 recomputed per tap
            stA[lane] = make_float4(a1, a2, a1 * a2, a1 * a1);
            stB[lane] = make_float4(b1, b2, b1 * b2, b1 * b1);
            if (hl) {
                stA[SPAN + lane] = make_float4(ha1, ha2, ha1 * ha2, ha1 * ha1);
                stB[SPAN + lane] = make_float4(hb1, hb2, hb1 * hb2, hb1 * hb1);
            }

            // prefetch next pair (wave-uniform ro: SALU add+min; +W folds to imm)
            ro = min(ro + 2 * W, rocap);
            a1 = q1[ro];     a2 = q2[ro];
            b1 = q1[ro + W]; b2 = q2[ro + W];
            if (hl) { ha1 = qh1[ro]; ha2 = qh2[ro]; hb1 = qh1[ro + W]; hb2 = qh2[ro + W]; }

            __builtin_amdgcn_wave_barrier();   // pin: writes above, reads below

            // two independent horizontal 11-tap chains (compiler interleaves)
            float hA0, hA1, hA2, hA3, hA4;
            float hB0, hB1, hB2, hB3, hB4;
            {
                const float4* ra = stA + lane;
                const float4* rb2 = stB + lane;
#pragma unroll
                for (int t = 0; t < 11; ++t) {
                    const float4 v = ra[t];          // ds_read_b128
                    const float w = g[t];
                    const float q22 = v.y * v.y;
                    if (t == 0) {
                        hA0 = w * v.x; hA1 = w * v.y; hA2 = w * v.w;
                        hA3 = w * q22; hA4 = w * v.z;
                    } else {
                        hA0 = fmaf(w, v.x, hA0); hA1 = fmaf(w, v.y, hA1);
                        hA2 = fmaf(w, v.w, hA2); hA3 = fmaf(w, q22, hA3);
                        hA4 = fmaf(w, v.z, hA4);
                    }
                }
#pragma unroll
                for (int t = 0; t < 11; ++t) {
                    const float4 v = rb2[t];         // ds_read_b128
                    const float w = g[t];
                    const float q22 = v.y * v.y;
                    if (t == 0) {
                        hB0 = w * v.x; hB1 = w * v.y; hB2 = w * v.w;
                        hB3 = w * q22; hB4 = w * v.z;
                    } else {
                        hB0 = fmaf(w, v.x, hB0); hB1 = fmaf(w, v.y, hB1);
                        hB2 = fmaf(w, v.w, hB2); hB3 = fmaf(w, q22, hB3);
                        hB4 = fmaf(w, v.z, hB4);
                    }
                }
            }

            __builtin_amdgcn_wave_barrier();   // pin: reads above next pair's writes

            // scatter row r (phase p): slot a==p gets mul (flushed last pair)
#pragma unroll
            for (int a = 0; a < 11; ++a) {
                const float w = g[(p - a + 11) % 11];
                if (a == p) {
                    a0[a] = w * hA0; a1q[a] = w * hA1; a2q[a] = w * hA2;
                    a3q[a] = w * hA3; a4q[a] = w * hA4;
                } else {
                    a0[a]  = fmaf(w, hA0, a0[a]);  a1q[a] = fmaf(w, hA1, a1q[a]);
                    a2q[a] = fmaf(w, hA2, a2q[a]); a3q[a] = fmaf(w, hA3, a3q[a]);
                    a4q[a] = fmaf(w, hA4, a4q[a]);
                }
            }

            // flush slot e1=(p+1)%11 = pp: output row oy = Y0 + r - 10
            if (r >= 10) {
                const int oy = Y0 + r - 10;
                if (oy >= oyb) {
                    const float m1 = a0[pp], m2 = a1q[pp];
                    const float m1s = m1 * m1, m2s = m2 * m2, m12 = m1 * m2;
                    const float sig1  = a2q[pp] - m1s;
                    const float sig2  = a3q[pp] - m2s;
                    const float sig12 = a4q[pp] - m12;
                    const float num = (2.f * m12 + C1c) * (2.f * sig12 + C2c);
                    const float den = (m1s + m2s + C1c) * (sig1 + sig2 + C2c);
                    lsum = fmaf(cmask, num * __builtin_amdgcn_rcpf(den), lsum);
                }
            }

            // scatter row r+1 (phase pp): slot a==pp gets mul (just flushed)
#pragma unroll
            for (int a = 0; a < 11; ++a) {
                const float w = g[(pp - a + 11) % 11];
                if (a == pp) {
                    a0[a] = w * hB0; a1q[a] = w * hB1; a2q[a] = w * hB2;
                    a3q[a] = w * hB3; a4q[a] = w * hB4;
                } else {
                    a0[a]  = fmaf(w, hB0, a0[a]);  a1q[a] = fmaf(w, hB1, a1q[a]);
                    a2q[a] = fmaf(w, hB2, a2q[a]); a3q[a] = fmaf(w, hB3, a3q[a]);
                    a4q[a] = fmaf(w, hB4, a4q[a]);
                }
            }

            // flush slot e2=(p+2)%11: output row oy2 = Y0 + r - 9
            if (r >= 10) {
                const int e2 = (p + 2) % 11;
                const int oy2 = Y0 + r - 9;
                if (oy2 >= oyb) {
                    const float m1 = a0[e2], m2 = a1q[e2];
                    const float m1s = m1 * m1, m2s = m2 * m2, m12 = m1 * m2;
                    const float sig1  = a2q[e2] - m1s;
                    const float sig2  = a3q[e2] - m2s;
                    const float sig12 = a4q[e2] - m12;
                    const float num = (2.f * m12 + C1c) * (2.f * sig12 + C2c);
                    const float den = (m1s + m2s + C1c) * (sig1 + sig2 + C2c);
                    lsum = fmaf(cmask, num * __builtin_amdgcn_rcpf(den), lsum);
                }
            }
        }
    }

    // per-wave reduce, then one cross-wave combine + one atomic per block
#pragma unroll
    for (int off = 32; off > 0; off >>= 1) lsum += __shfl_down(lsum, off, 64);
    if (lane == 0) wsum[wid] = lsum;
    __syncthreads();
    if (tid == 0) {
        const float inv_count = 1.0f / (3.0f * (float)OUT_H * (float)OUT_W);
        const float total = (wsum[0] + wsum[1] + wsum[2] + wsum[3]) * inv_count;
        atomicAdd(&out[plane / 3], total);
    }
}

__global__ void zero_out(float* out, int n) {
    int i = threadIdx.x + blockIdx.x * blockDim.x;
    if (i < n) out[i] = 0.f;
}

extern "C" void kernel_launch(void* const* d_in, const int* in_sizes, int n_in,
                              void* d_out, int out_size, void* d_ws, size_t ws_size,
                              hipStream_t stream) {
    const float* img1 = (const float*)d_in[0];
    const float* img2 = (const float*)d_in[1];
    float* out = (float*)d_out;

    zero_out<<<1, 64, 0, stream>>>(out, out_size);

    const int nplanes = in_sizes[0] / (H * W);          // 96
    dim3 grid(W / 256,                                  // 2 col-tiles (4 strips each)
              (OUT_H + TH - 1) / TH,                    // 4 row-tiles
              nplanes);                                 // 96 planes -> 768 blocks
    ssim_kernel<<<grid, 256, 0, stream>>>(img1, img2, out);
}